// Round 1
// baseline (599.092 us; speedup 1.0000x reference)
//
#include <hip/hip_runtime.h>
#include <hip/hip_bf16.h>
#include <math.h>

#define NSPK 2048
#define G 10
#define D 256
#define NG (NSPK * G)

#define BM 64
#define BN 64
#define BK 32

// ---------------- Kernel A: per-speaker prep ----------------
// For speaker n: S = sum_g x[n,g,:]
//   centroid = S/G ; chat = centroid / max(||centroid||, eps)   (c_norm folded in)
//   per g: x_norm, exclusive-centroid cosine -> diag logit (w*clip(cos)+b)
__global__ __launch_bounds__(256) void prep_kernel(
    const float* __restrict__ x, const float* __restrict__ wp, const float* __restrict__ bp,
    float* __restrict__ chat, float* __restrict__ inv_xnorm, float* __restrict__ diag_logit)
{
    const int n = blockIdx.x;
    const int t = threadIdx.x;  // d index, 0..255
    const float* xr = x + (size_t)n * G * D;

    float xg[G];
    float S = 0.f;
    #pragma unroll
    for (int g = 0; g < G; ++g) { xg[g] = xr[g * D + t]; S += xg[g]; }

    float vals[21];
    vals[0] = S * S;
    #pragma unroll
    for (int g = 0; g < G; ++g) { vals[1 + g] = xg[g] * xg[g]; vals[11 + g] = xg[g] * S; }

    // wave reduce each of the 21 values
    #pragma unroll
    for (int i = 0; i < 21; ++i) {
        float v = vals[i];
        #pragma unroll
        for (int off = 1; off < 64; off <<= 1) v += __shfl_xor(v, off);
        vals[i] = v;
    }
    __shared__ float red[4][21];
    __shared__ float tot[21];
    const int wave = t >> 6, lane = t & 63;
    if (lane == 0) {
        #pragma unroll
        for (int i = 0; i < 21; ++i) red[wave][i] = vals[i];
    }
    __syncthreads();
    if (t < 21) tot[t] = red[0][t] + red[1][t] + red[2][t] + red[3][t];
    __syncthreads();

    const float SS = tot[0];
    const float c_norm = fmaxf(sqrtf(SS) * (1.0f / G), 1e-8f);
    chat[(size_t)n * D + t] = (S * (1.0f / G)) / c_norm;

    if (t < G) {
        const int g = t;
        const float w = *wp, b = *bp;
        const float xx = tot[1 + g], xs = tot[11 + g];
        const float x_norm = fmaxf(sqrtf(xx), 1e-8f);
        const float dotxe = (xs - xx) * (1.0f / (G - 1));
        const float ee = (SS - 2.f * xs + xx) * (1.0f / ((G - 1) * (G - 1)));
        const float e_norm = fmaxf(sqrtf(ee), 1e-8f);
        float cosd = dotxe / (x_norm * e_norm);
        cosd = fmaxf(cosd, 1e-6f);
        diag_logit[n * G + g] = w * cosd + b;
        inv_xnorm[n * G + g] = 1.0f / x_norm;
    }
}

// ---------------- Kernel B: GEMM (x . chat^T) + fused online log-softmax/argmax ----
__global__ __launch_bounds__(256) void gemm_softmax_kernel(
    const float* __restrict__ x, const float* __restrict__ chat,
    const float* __restrict__ inv_xnorm, const float* __restrict__ diag_logit,
    const float* __restrict__ wp, const float* __restrict__ bp,
    float* __restrict__ row_loss, float* __restrict__ row_correct)
{
    __shared__ float As[BK][BM + 4];
    __shared__ float Bs[BK][BN + 4];
    __shared__ float red_m[BM][17];
    __shared__ float red_s[BM][17];
    __shared__ int   red_a[BM][17];

    const int tid = threadIdx.x;
    const int tx = tid & 15, ty = tid >> 4;
    const int r0 = blockIdx.x * BM;
    const float w = *wp, b = *bp;

    int rows[4]; float rinv[4]; int labels[4];
    #pragma unroll
    for (int i = 0; i < 4; ++i) {
        rows[i] = r0 + ty * 4 + i;
        rinv[i] = inv_xnorm[rows[i]];
        labels[i] = rows[i] / G;
    }
    float m_run[4], s_run[4]; int a_run[4];
    #pragma unroll
    for (int i = 0; i < 4; ++i) { m_run[i] = -INFINITY; s_run[i] = 0.f; a_run[i] = 0; }

    for (int ct = 0; ct < NSPK / BN; ++ct) {
        const int c0 = ct * BN;
        float acc[4][4];
        #pragma unroll
        for (int i = 0; i < 4; ++i)
            #pragma unroll
            for (int j = 0; j < 4; ++j) acc[i][j] = 0.f;

        for (int kt = 0; kt < D / BK; ++kt) {
            const int k0 = kt * BK;
            // load A tile (64 rows x 32 k) and B tile, 2 float4 per thread each
            #pragma unroll
            for (int p = 0; p < 2; ++p) {
                const int f = tid + p * 256;   // 0..511
                const int row = f >> 3;
                const int k4 = (f & 7) * 4;
                float4 v = *(const float4*)(x + (size_t)(r0 + row) * D + k0 + k4);
                As[k4 + 0][row] = v.x; As[k4 + 1][row] = v.y;
                As[k4 + 2][row] = v.z; As[k4 + 3][row] = v.w;
                float4 u = *(const float4*)(chat + (size_t)(c0 + row) * D + k0 + k4);
                Bs[k4 + 0][row] = u.x; Bs[k4 + 1][row] = u.y;
                Bs[k4 + 2][row] = u.z; Bs[k4 + 3][row] = u.w;
            }
            __syncthreads();
            #pragma unroll
            for (int k = 0; k < BK; ++k) {
                const float4 av = *(const float4*)&As[k][ty * 4];
                const float4 bv = *(const float4*)&Bs[k][tx * 4];
                const float aa[4] = {av.x, av.y, av.z, av.w};
                const float bb[4] = {bv.x, bv.y, bv.z, bv.w};
                #pragma unroll
                for (int i = 0; i < 4; ++i)
                    #pragma unroll
                    for (int j = 0; j < 4; ++j) acc[i][j] = fmaf(aa[i], bb[j], acc[i][j]);
            }
            __syncthreads();
        }
        // online softmax update over this column tile
        #pragma unroll
        for (int i = 0; i < 4; ++i) {
            #pragma unroll
            for (int j = 0; j < 4; ++j) {
                const int m = c0 + tx * 4 + j;
                float cosv = acc[i][j] * rinv[i];
                cosv = fmaxf(cosv, 1e-6f);
                float logit = w * cosv + b;
                if (m == labels[i]) logit = diag_logit[rows[i]];
                if (logit > m_run[i]) {
                    s_run[i] = s_run[i] * __expf(m_run[i] - logit) + 1.0f;
                    m_run[i] = logit;
                    a_run[i] = m;
                } else {
                    s_run[i] += __expf(logit - m_run[i]);
                }
            }
        }
    }

    // merge the 16 column-thread partials per row
    #pragma unroll
    for (int i = 0; i < 4; ++i) {
        red_m[ty * 4 + i][tx] = m_run[i];
        red_s[ty * 4 + i][tx] = s_run[i];
        red_a[ty * 4 + i][tx] = a_run[i];
    }
    __syncthreads();
    if (tid < BM) {
        const int rr = tid;
        float M = -INFINITY; int A = 0x7fffffff;
        #pragma unroll
        for (int t2 = 0; t2 < 16; ++t2) {
            const float mv = red_m[rr][t2];
            const int av = red_a[rr][t2];
            if (mv > M || (mv == M && av < A)) { M = mv; A = av; }
        }
        float Ssum = 0.f;
        #pragma unroll
        for (int t2 = 0; t2 < 16; ++t2) Ssum += red_s[rr][t2] * __expf(red_m[rr][t2] - M);
        const int r = r0 + rr;
        row_loss[r] = M + logf(Ssum) - diag_logit[r];
        row_correct[r] = (A == r / G) ? 1.0f : 0.0f;
    }
}

// ---------------- Kernel C: final reduction ----------------
__global__ __launch_bounds__(256) void finalize_kernel(
    const float* __restrict__ row_loss, const float* __restrict__ row_correct,
    float* __restrict__ out)
{
    const int t = threadIdx.x;
    float ls = 0.f, cs = 0.f;
    for (int i = t; i < NG; i += 256) { ls += row_loss[i]; cs += row_correct[i]; }
    #pragma unroll
    for (int off = 1; off < 64; off <<= 1) { ls += __shfl_xor(ls, off); cs += __shfl_xor(cs, off); }
    __shared__ float rl[4], rc[4];
    const int wave = t >> 6, lane = t & 63;
    if (lane == 0) { rl[wave] = ls; rc[wave] = cs; }
    __syncthreads();
    if (t == 0) {
        const float L = rl[0] + rl[1] + rl[2] + rl[3];
        const float C = rc[0] + rc[1] + rc[2] + rc[3];
        out[0] = L / (float)NG;
        out[1] = 100.0f * C / (float)NG;
    }
}

extern "C" void kernel_launch(void* const* d_in, const int* in_sizes, int n_in,
                              void* d_out, int out_size, void* d_ws, size_t ws_size,
                              hipStream_t stream) {
    const float* x  = (const float*)d_in[0];
    const float* wp = (const float*)d_in[1];
    const float* bp = (const float*)d_in[2];

    float* ws = (float*)d_ws;
    float* chat       = ws;                       // 2048*256 = 524288
    float* inv_xnorm  = ws + 524288;              // 20480
    float* diag_logit = ws + 524288 + 20480;      // 20480
    float* row_loss   = ws + 524288 + 40960;      // 20480
    float* row_corr   = ws + 524288 + 61440;      // 20480

    prep_kernel<<<NSPK, 256, 0, stream>>>(x, wp, bp, chat, inv_xnorm, diag_logit);
    gemm_softmax_kernel<<<NG / BM, 256, 0, stream>>>(x, chat, inv_xnorm, diag_logit,
                                                     wp, bp, row_loss, row_corr);
    finalize_kernel<<<1, 256, 0, stream>>>(row_loss, row_corr, (float*)d_out);
}

// Round 2
// 135.109 us; speedup vs baseline: 4.4341x; 4.4341x over previous
//
#include <hip/hip_runtime.h>
#include <hip/hip_bf16.h>
#include <math.h>

#define NSPK 2048
#define G 10
#define D 256
#define NG (NSPK * G)
#define BM 32

typedef __attribute__((ext_vector_type(8))) short bf16x8;
typedef __attribute__((ext_vector_type(16))) float f32x16;

// ---------------- Kernel A: per-speaker prep ----------------
// Emits: xb  = bf16( x[n,g,:] / max(||x||,eps) )        [NG, D]
//        cb  = bf16( centroid / max(||centroid||,eps) ) [NSPK, D]
//        diag_logit[n,g] = w*clip(cos(x, exc_centroid)) + b
__global__ __launch_bounds__(256) void prep_kernel(
    const float* __restrict__ x, const float* __restrict__ wp, const float* __restrict__ bp,
    short* __restrict__ xb, short* __restrict__ cb, float* __restrict__ diag_logit)
{
    const int n = blockIdx.x;
    const int t = threadIdx.x;  // d index, 0..255
    const float* xr = x + (size_t)n * G * D;

    float xg[G];
    float S = 0.f;
    #pragma unroll
    for (int g = 0; g < G; ++g) { xg[g] = xr[g * D + t]; S += xg[g]; }

    float vals[21];
    vals[0] = S * S;
    #pragma unroll
    for (int g = 0; g < G; ++g) { vals[1 + g] = xg[g] * xg[g]; vals[11 + g] = xg[g] * S; }

    #pragma unroll
    for (int i = 0; i < 21; ++i) {
        float v = vals[i];
        #pragma unroll
        for (int off = 1; off < 64; off <<= 1) v += __shfl_xor(v, off);
        vals[i] = v;
    }
    __shared__ float red[4][21];
    __shared__ float tot[21];
    const int wave = t >> 6, lane = t & 63;
    if (lane == 0) {
        #pragma unroll
        for (int i = 0; i < 21; ++i) red[wave][i] = vals[i];
    }
    __syncthreads();
    if (t < 21) tot[t] = red[0][t] + red[1][t] + red[2][t] + red[3][t];
    __syncthreads();

    const float SS = tot[0];
    const float c_norm = fmaxf(sqrtf(SS) * (1.0f / G), 1e-8f);
    cb[(size_t)n * D + t] = __bfloat16_as_ushort(__float2bfloat16((S * (1.0f / G)) / c_norm));

    // normalized x rows -> bf16
    #pragma unroll
    for (int g = 0; g < G; ++g) {
        const float xn = fmaxf(sqrtf(tot[1 + g]), 1e-8f);
        xb[(size_t)(n * G + g) * D + t] =
            __bfloat16_as_ushort(__float2bfloat16(xg[g] / xn));
    }

    if (t < G) {
        const int g = t;
        const float w = *wp, b = *bp;
        const float xx = tot[1 + g], xs = tot[11 + g];
        const float x_norm = fmaxf(sqrtf(xx), 1e-8f);
        const float dotxe = (xs - xx) * (1.0f / (G - 1));
        const float ee = (SS - 2.f * xs + xx) * (1.0f / ((G - 1) * (G - 1)));
        const float e_norm = fmaxf(sqrtf(ee), 1e-8f);
        float cosd = dotxe / (x_norm * e_norm);
        cosd = fmaxf(cosd, 1e-6f);
        diag_logit[n * G + g] = w * cosd + b;
    }
}

// ---------------- Kernel B: MFMA GEMM + fused online log-sum-exp/argmax ----
// Swapped operands: D[i][j] = sum_k cb[cbase+i][k] * xb[r0+j][k]
//   -> lane owns ONE x-row (j = lane&31), 16 centroid-cols per iter.
// logit <= w*1+b = 5 (cos <= ~1), so fixed-max LSE: s = sum exp(logit-5).
__global__ __launch_bounds__(256) void gemm_softmax_kernel(
    const short* __restrict__ xb, const short* __restrict__ cb,
    const float* __restrict__ diag_logit,
    const float* __restrict__ wp, const float* __restrict__ bp,
    float* __restrict__ row_loss, float* __restrict__ row_correct)
{
    const int tid = threadIdx.x;
    const int wv = tid >> 6, lane = tid & 63;
    const int l31 = lane & 31, l5 = lane >> 5;
    const int r0 = blockIdx.x * BM;
    const int myrow = r0 + l31;
    const float w = *wp, b = *bp;
    const float dlog = diag_logit[myrow];
    const int lab = myrow / G;

    // resident normalized-x fragments: 16 k-steps x 8 bf16
    bf16x8 xf[16];
    const short* xrow = xb + (size_t)myrow * D + l5 * 8;
    #pragma unroll
    for (int ks = 0; ks < 16; ++ks)
        xf[ks] = *(const bf16x8*)(xrow + ks * 16);

    float s = 0.f, lmax = -INFINITY;
    int aidx = 0;

    for (int it = 0; it < NSPK / 128; ++it) {      // 16 iters, 128 cols each
        const int cbase = it * 128 + wv * 32;
        const short* crow = cb + (size_t)(cbase + l31) * D + l5 * 8;
        bf16x8 cf[16];
        #pragma unroll
        for (int ks = 0; ks < 16; ++ks)
            cf[ks] = *(const bf16x8*)(crow + ks * 16);

        f32x16 acc = {0,0,0,0,0,0,0,0,0,0,0,0,0,0,0,0};
        #pragma unroll
        for (int ks = 0; ks < 16; ++ks)
            acc = __builtin_amdgcn_mfma_f32_32x32x16_bf16(cf[ks], xf[ks], acc, 0, 0, 0);

        #pragma unroll
        for (int reg = 0; reg < 16; ++reg) {
            const int col = cbase + ((reg & 3) + 8 * (reg >> 2) + 4 * l5);
            const float cosv = fmaxf(acc[reg], 1e-6f);
            float logit = fmaf(w, cosv, b);
            logit = (col == lab) ? dlog : logit;
            s += __expf(logit - 5.0f);
            const bool gt = logit > lmax;
            lmax = gt ? logit : lmax;
            aidx = gt ? col : aidx;
        }
    }

    // merge the lane^32 partner (other half of each col tile)
    {
        const float om = __shfl_xor(lmax, 32);
        const int   oa = __shfl_xor(aidx, 32);
        const float os = __shfl_xor(s, 32);
        s += os;
        const bool take = (om > lmax) || (om == lmax && oa < aidx);
        lmax = take ? om : lmax;
        aidx = take ? oa : aidx;
    }

    __shared__ float sm[BM][4], ss[BM][4];
    __shared__ int   sa[BM][4];
    if (lane < 32) { sm[l31][wv] = lmax; ss[l31][wv] = s; sa[l31][wv] = aidx; }
    __syncthreads();
    if (tid < BM) {
        float M = -INFINITY, S = 0.f;
        int A = 0x7fffffff;
        #pragma unroll
        for (int v = 0; v < 4; ++v) {
            const float mv = sm[tid][v];
            const int av = sa[tid][v];
            if (mv > M || (mv == M && av < A)) { M = mv; A = av; }
        }
        #pragma unroll
        for (int v = 0; v < 4; ++v) S += ss[tid][v];
        const int r = r0 + tid;
        row_loss[r] = 5.0f + logf(S) - diag_logit[r];
        row_correct[r] = (A == r / G) ? 1.0f : 0.0f;
    }
}

// ---------------- Kernel C: final reduction ----------------
__global__ __launch_bounds__(256) void finalize_kernel(
    const float* __restrict__ row_loss, const float* __restrict__ row_correct,
    float* __restrict__ out)
{
    const int t = threadIdx.x;
    float ls = 0.f, cs = 0.f;
    for (int i = t; i < NG; i += 256) { ls += row_loss[i]; cs += row_correct[i]; }
    #pragma unroll
    for (int off = 1; off < 64; off <<= 1) { ls += __shfl_xor(ls, off); cs += __shfl_xor(cs, off); }
    __shared__ float rl[4], rc[4];
    const int wave = t >> 6, lane = t & 63;
    if (lane == 0) { rl[wave] = ls; rc[wave] = cs; }
    __syncthreads();
    if (t == 0) {
        const float L = rl[0] + rl[1] + rl[2] + rl[3];
        const float C = rc[0] + rc[1] + rc[2] + rc[3];
        out[0] = L / (float)NG;
        out[1] = 100.0f * C / (float)NG;
    }
}

extern "C" void kernel_launch(void* const* d_in, const int* in_sizes, int n_in,
                              void* d_out, int out_size, void* d_ws, size_t ws_size,
                              hipStream_t stream) {
    const float* x  = (const float*)d_in[0];
    const float* wp = (const float*)d_in[1];
    const float* bp = (const float*)d_in[2];

    short* xb = (short*)d_ws;                         // NG*D shorts   = 10.0 MB
    short* cb = xb + (size_t)NG * D;                  // NSPK*D shorts = 1.0 MB
    float* diag_logit = (float*)(cb + (size_t)NSPK * D);  // NG floats
    float* row_loss = diag_logit + NG;
    float* row_corr = row_loss + NG;

    prep_kernel<<<NSPK, 256, 0, stream>>>(x, wp, bp, xb, cb, diag_logit);
    gemm_softmax_kernel<<<NG / BM, 256, 0, stream>>>(xb, cb, diag_logit,
                                                     wp, bp, row_loss, row_corr);
    finalize_kernel<<<1, 256, 0, stream>>>(row_loss, row_corr, (float*)d_out);
}

// Round 3
// 83.979 us; speedup vs baseline: 7.1338x; 1.6088x over previous
//
#include <hip/hip_runtime.h>
#include <hip/hip_bf16.h>
#include <math.h>

#define NSPK 2048
#define G 10
#define D 256
#define NG (NSPK * G)

typedef __attribute__((ext_vector_type(8))) short bf16x8;
typedef __attribute__((ext_vector_type(16))) float f32x16;

// ---------------- Kernel A: per-speaker prep ----------------
__global__ __launch_bounds__(256) void prep_kernel(
    const float* __restrict__ x, const float* __restrict__ wp, const float* __restrict__ bp,
    short* __restrict__ xb, short* __restrict__ cb, float* __restrict__ diag_logit)
{
    const int n = blockIdx.x;
    const int t = threadIdx.x;  // d index, 0..255
    const float* xr = x + (size_t)n * G * D;

    float xg[G];
    float S = 0.f;
    #pragma unroll
    for (int g = 0; g < G; ++g) { xg[g] = xr[g * D + t]; S += xg[g]; }

    float vals[21];
    vals[0] = S * S;
    #pragma unroll
    for (int g = 0; g < G; ++g) { vals[1 + g] = xg[g] * xg[g]; vals[11 + g] = xg[g] * S; }

    #pragma unroll
    for (int i = 0; i < 21; ++i) {
        float v = vals[i];
        #pragma unroll
        for (int off = 1; off < 64; off <<= 1) v += __shfl_xor(v, off);
        vals[i] = v;
    }
    __shared__ float red[4][21];
    __shared__ float tot[21];
    const int wave = t >> 6, lane = t & 63;
    if (lane == 0) {
        #pragma unroll
        for (int i = 0; i < 21; ++i) red[wave][i] = vals[i];
    }
    __syncthreads();
    if (t < 21) tot[t] = red[0][t] + red[1][t] + red[2][t] + red[3][t];
    __syncthreads();

    const float SS = tot[0];
    const float c_norm = fmaxf(sqrtf(SS) * (1.0f / G), 1e-8f);
    cb[(size_t)n * D + t] = __bfloat16_as_ushort(__float2bfloat16((S * (1.0f / G)) / c_norm));

    #pragma unroll
    for (int g = 0; g < G; ++g) {
        const float xn = fmaxf(sqrtf(tot[1 + g]), 1e-8f);
        xb[(size_t)(n * G + g) * D + t] =
            __bfloat16_as_ushort(__float2bfloat16(xg[g] / xn));
    }

    if (t < G) {
        const int g = t;
        const float w = *wp, b = *bp;
        const float xx = tot[1 + g], xs = tot[11 + g];
        const float x_norm = fmaxf(sqrtf(xx), 1e-8f);
        const float dotxe = (xs - xx) * (1.0f / (G - 1));
        const float ee = (SS - 2.f * xs + xx) * (1.0f / ((G - 1) * (G - 1)));
        const float e_norm = fmaxf(sqrtf(ee), 1e-8f);
        float cosd = dotxe / (x_norm * e_norm);
        cosd = fmaxf(cosd, 1e-6f);
        diag_logit[n * G + g] = w * cosd + b;
    }
}

// ---------------- Kernel B: LDS-staged MFMA GEMM + fused fixed-max LSE ----
// Block: 128 x-rows (4 waves x 32) x 512 cols (16 tiles of 32).
// Per tile: cb[32 rows][256] staged to LDS, coalesced global_load_lds,
// XOR-swizzled (slot ^= row&31) so ds_read_b128 is conflict-free.
// Swapped MFMA (A=cb, B=xb): lane owns one x-row; LSE vs fixed max 5.
__global__ __launch_bounds__(256) void gemm_softmax_kernel(
    const short* __restrict__ xb, const short* __restrict__ cb,
    const float* __restrict__ diag_logit,
    const float* __restrict__ wp, const float* __restrict__ bp,
    float* __restrict__ pm, float* __restrict__ ps, int* __restrict__ pa)
{
    __shared__ __align__(16) unsigned short stage[2][8192];   // 2 x 16 KB

    const int tid = threadIdx.x;
    const int wv = tid >> 6, lane = tid & 63;
    const int l31 = lane & 31, l5 = lane >> 5;
    const int rt = blockIdx.x >> 2, cs = blockIdx.x & 3;
    const int r0 = rt * 128, c0 = cs * 512;
    const int myrow = r0 + wv * 32 + l31;
    const float w = *wp, b = *bp;
    const float dlog = diag_logit[myrow];
    const int lab = myrow / G;

    // resident normalized-x fragments (B operand): 16 k-steps x 8 bf16
    bf16x8 xf[16];
    const short* xrow = xb + (size_t)myrow * D + l5 * 8;
    #pragma unroll
    for (int ks = 0; ks < 16; ++ks)
        xf[ks] = *(const bf16x8*)(xrow + ks * 16);

    // staging source offsets (pre-swizzled): 4 calls/wave, 16B/lane each
    const unsigned char* cbb = (const unsigned char*)cb;
    size_t src_off[4];
    #pragma unroll
    for (int c = 0; c < 4; ++c) {
        const int slot = wv * 256 + c * 64 + lane;   // 16B-slot index, 0..1023
        const int i = slot >> 5;                      // row within 32-row tile
        const int w32 = slot & 31;                    // slot within row
        src_off[c] = (size_t)(c0 + i) * 512 + (size_t)((w32 ^ i) << 4);
    }

    #define STAGE(bufi, tt) do {                                               \
        const unsigned char* base_ = cbb + (size_t)(tt) * 16384;               \
        _Pragma("unroll")                                                      \
        for (int c_ = 0; c_ < 4; ++c_) {                                       \
            __builtin_amdgcn_global_load_lds(                                  \
                (const __attribute__((address_space(1))) void*)(base_ + src_off[c_]), \
                (__attribute__((address_space(3))) void*)                      \
                    ((unsigned char*)&stage[bufi][0] + (wv * 4 + c_) * 1024),  \
                16, 0, 0);                                                     \
        }                                                                      \
    } while (0)

    float s = 0.f, lmax = -INFINITY;
    int aidx = 0;
    const int rbase = l31 * 32;

    STAGE(0, 0);
    __syncthreads();

    for (int t = 0; t < 16; ++t) {
        const int bsel = t & 1;
        if (t < 15) STAGE(bsel ^ 1, t + 1);

        f32x16 acc = {0,0,0,0,0,0,0,0,0,0,0,0,0,0,0,0};
        #pragma unroll
        for (int ks = 0; ks < 16; ++ks) {
            const int slot = rbase + ((2 * ks + l5) ^ l31);
            const bf16x8 cf = *(const bf16x8*)(&stage[bsel][slot * 8]);
            acc = __builtin_amdgcn_mfma_f32_32x32x16_bf16(cf, xf[ks], acc, 0, 0, 0);
        }

        const int ct0 = c0 + t * 32;
        #pragma unroll
        for (int reg = 0; reg < 16; ++reg) {
            const int col = ct0 + ((reg & 3) + 8 * (reg >> 2) + 4 * l5);
            const float cosv = fmaxf(acc[reg], 1e-6f);
            float logit = fmaf(w, cosv, b);
            logit = (col == lab) ? dlog : logit;
            s += __expf(logit - 5.0f);
            const bool gt = logit > lmax;
            lmax = gt ? logit : lmax;
            aidx = gt ? col : aidx;
        }
        __syncthreads();
    }
    #undef STAGE

    // merge the lane^32 partner (other half of k / col coverage)
    {
        const float om = __shfl_xor(lmax, 32);
        const int   oa = __shfl_xor(aidx, 32);
        const float os = __shfl_xor(s, 32);
        s += os;
        const bool take = (om > lmax) || (om == lmax && oa < aidx);
        lmax = take ? om : lmax;
        aidx = take ? oa : aidx;
    }
    if (lane < 32) {
        pm[cs * NG + myrow] = lmax;
        ps[cs * NG + myrow] = s;
        pa[cs * NG + myrow] = aidx;
    }
}

// ---------------- Kernel C: merge column-split partials ----------------
__global__ __launch_bounds__(256) void merge_kernel(
    const float* __restrict__ pm, const float* __restrict__ ps, const int* __restrict__ pa,
    const float* __restrict__ diag_logit,
    float* __restrict__ row_loss, float* __restrict__ row_correct)
{
    const int r = blockIdx.x * 256 + threadIdx.x;
    float M = -INFINITY, S = 0.f;
    int A = 0x7fffffff;
    #pragma unroll
    for (int c = 0; c < 4; ++c) {
        const float mv = pm[c * NG + r];
        const int av = pa[c * NG + r];
        if (mv > M || (mv == M && av < A)) { M = mv; A = av; }
        S += ps[c * NG + r];
    }
    row_loss[r] = 5.0f + logf(S) - diag_logit[r];
    row_correct[r] = (A == r / G) ? 1.0f : 0.0f;
}

// ---------------- Kernel D: final reduction ----------------
__global__ __launch_bounds__(256) void finalize_kernel(
    const float* __restrict__ row_loss, const float* __restrict__ row_correct,
    float* __restrict__ out)
{
    const int t = threadIdx.x;
    float ls = 0.f, cs = 0.f;
    for (int i = t; i < NG; i += 256) { ls += row_loss[i]; cs += row_correct[i]; }
    #pragma unroll
    for (int off = 1; off < 64; off <<= 1) { ls += __shfl_xor(ls, off); cs += __shfl_xor(cs, off); }
    __shared__ float rl[4], rc[4];
    const int wave = t >> 6, lane = t & 63;
    if (lane == 0) { rl[wave] = ls; rc[wave] = cs; }
    __syncthreads();
    if (t == 0) {
        const float L = rl[0] + rl[1] + rl[2] + rl[3];
        const float C = rc[0] + rc[1] + rc[2] + rc[3];
        out[0] = L / (float)NG;
        out[1] = 100.0f * C / (float)NG;
    }
}

extern "C" void kernel_launch(void* const* d_in, const int* in_sizes, int n_in,
                              void* d_out, int out_size, void* d_ws, size_t ws_size,
                              hipStream_t stream) {
    const float* x  = (const float*)d_in[0];
    const float* wp = (const float*)d_in[1];
    const float* bp = (const float*)d_in[2];

    short* xb = (short*)d_ws;                              // NG*D shorts   = 10.5 MB
    short* cb = xb + (size_t)NG * D;                       // NSPK*D shorts = 1.05 MB
    float* diag_logit = (float*)(cb + (size_t)NSPK * D);   // NG floats
    float* pm = diag_logit + NG;                           // 4*NG
    float* ps = pm + 4 * NG;                               // 4*NG
    int*   pa = (int*)(ps + 4 * NG);                       // 4*NG
    float* row_loss = (float*)(pa + 4 * NG);               // NG
    float* row_corr = row_loss + NG;                       // NG

    prep_kernel<<<NSPK, 256, 0, stream>>>(x, wp, bp, xb, cb, diag_logit);
    gemm_softmax_kernel<<<640, 256, 0, stream>>>(xb, cb, diag_logit, wp, bp, pm, ps, pa);
    merge_kernel<<<NG / 256, 256, 0, stream>>>(pm, ps, pa, diag_logit, row_loss, row_corr);
    finalize_kernel<<<1, 256, 0, stream>>>(row_loss, row_corr, (float*)d_out);
}